// Round 4
// baseline (162.678 us; speedup 1.0000x reference)
//
#include <hip/hip_runtime.h>
#include <hip/hip_bf16.h>
#include <math.h>

// Problem constants
#define BB    8
#define HH    160
#define WW    256
#define CC    700
#define KK    250
#define NBINS 750
#define NHIST 30
#define NJIT  60
#define NFRM  90
#define PP    (HH*WW)      // 40960
#define TOUT  500
#define MAGIC (400.0f/750.0f)

// Padded GEMM dims
#define MPAD  512          // 480 -> 512 (32 tiles of 16)
#define NPAD  768          // 700 -> 768 (48 tiles of 16)
#define NKT   1280         // K / 32
#define KSPLIT 20
#define NSTEP 32           // 64 ktiles per split / 2 per BK=64 step
#define PACKA_BLKS (32*NKT/4)   // 10240

typedef __attribute__((ext_vector_type(8))) short short8;
typedef __attribute__((ext_vector_type(4))) short short4v;
typedef __attribute__((ext_vector_type(4))) float f32x4;

__device__ __forceinline__ unsigned short f2bf(float x) {
    unsigned u = __builtin_bit_cast(unsigned, x);
    u += 0x7fffu + ((u >> 16) & 1u);   // RNE
    return (unsigned short)(u >> 16);
}

__device__ __forceinline__ void gload16(const void* g, void* l) {
    __builtin_amdgcn_global_load_lds(
        (const __attribute__((address_space(1))) unsigned int*)g,
        (__attribute__((address_space(3))) unsigned int*)l, 16, 0, 0);
}

// LDS byte-offset swizzle (involution, touches bank bits 4-6 only)
__device__ __forceinline__ int SWZ(int X) { return X ^ (((X >> 8) & 7) << 4); }

// ---------------------------------------------------------------------------
// pack_a_k: jittered image -> bf16, fragment-ready layout (writes coalesced;
// reads hit the 1.25MB L2-resident image).
// Ap[((mt*1280 + kt)*64 + l)*8 + j] = A[mt*16 + (l&15)][kt*32 + 8*(l>>4) + j]
// ---------------------------------------------------------------------------
__global__ __launch_bounds__(256) void pack_a_k(
    const float* __restrict__ img, const int* __restrict__ eye,
    unsigned short* __restrict__ Ap)
{
    int tid = blockIdx.x*256 + threadIdx.x;
    int l   = tid & 63;
    int wid = tid >> 6;                 // mt*1280 + kt
    int kt  = wid % NKT;
    int mt  = wid / NKT;                // 0..31
    int m   = mt*16 + (l & 15);
    int kb  = kt*32 + 8*(l >> 4);

    unsigned short out[8] = {0,0,0,0,0,0,0,0};
    if (m < 480) {
        int b = m / 60, f = m % 60;
        int dy = eye[(b*NJIT + f)*2 + 0];
        int dx = eye[(b*NJIT + f)*2 + 1];
        int r  = (kb >> 8) + dy;
        int c0 = (kb & 255) + dx;
        if (r < HH) {
            const float* row = img + (size_t)b*PP + r*WW;
            #pragma unroll
            for (int j = 0; j < 8; ++j) {
                int c = c0 + j;
                if (c < WW) out[j] = f2bf(row[c]);
            }
        }
    }
    *(short8*)(Ap + ((size_t)wid*64 + l)*8) = *(short8*)out;
}

// ---------------------------------------------------------------------------
// pack_b_k: filters fp32 -> bf16 fragment layout via LDS transpose.
// Block = 16 rows x 512 k (16 ktiles). Reads: 1KB contiguous per wave-load.
// LDS staged in fragment layout (XOR-swizzled, write=4/bank, read=8/bank
// = both at the wave64 floor). Writes: contiguous 1KB wave-stores.
// ---------------------------------------------------------------------------
__global__ __launch_bounds__(256) void pack_b_k(
    const float* __restrict__ filt, unsigned short* __restrict__ Bp)
{
    __shared__ unsigned short lds[8192];   // 16KB
    const int t = threadIdx.x, l = t & 63, w = t >> 6;
    const int nt    = blockIdx.x / 80;          // 0..47
    const int kt0   = (blockIdx.x % 80) * 16;   // ktile base
    const int kbase = kt0 * 32;                 // element base

    #pragma unroll
    for (int sub = 0; sub < 4; ++sub) {
        int r = sub*4 + w;              // 0..15
        int n = nt*16 + r;
        float4 va = make_float4(0.f,0.f,0.f,0.f), vb = va;
        if (n < CC) {
            const float* row = filt + (size_t)n*PP + kbase;
            va = *(const float4*)(row + l*4);
            vb = *(const float4*)(row + l*4 + 256);
        }
        short4v pa, pb;
        pa[0]=(short)f2bf(va.x); pa[1]=(short)f2bf(va.y);
        pa[2]=(short)f2bf(va.z); pa[3]=(short)f2bf(va.w);
        pb[0]=(short)f2bf(vb.x); pb[1]=(short)f2bf(vb.y);
        pb[2]=(short)f2bf(vb.z); pb[3]=(short)f2bf(vb.w);
        // logical frag byte offset: X(r,k) = (k>>5)*1024 + ((k>>3)&3)*256
        //                                    + r*16 + (k&7)*2
        int k0a = l*4, k0b = l*4 + 256;
        int Xa = ((k0a>>5)<<10) | (((k0a>>3)&3)<<8) | (r<<4) | ((k0a&7)<<1);
        int Xb = ((k0b>>5)<<10) | (((k0b>>3)&3)<<8) | (r<<4) | ((k0b&7)<<1);
        *(short4v*)((char*)lds + SWZ(Xa)) = pa;
        *(short4v*)((char*)lds + SWZ(Xb)) = pb;
    }
    __syncthreads();

    unsigned short* outp = Bp + ((size_t)nt*NKT + kt0)*512;  // shorts
    #pragma unroll
    for (int i = 0; i < 4; ++i) {
        int X = i*4096 + t*16;          // instruction-major: 1KB/wave stores
        short8 v = *(const short8*)((const char*)lds + SWZ(X));
        *(short8*)((char*)outp + X) = v;
    }
}

// ---------------------------------------------------------------------------
// gemm_mfma: bf16 MFMA 16x16x32. BM=BN=128, BK=64, 4 waves (2x2), each a
// 64x64 sub-tile (4x4 frags). grid (4, 6, KSPLIT) = 480 blocks.
// ---------------------------------------------------------------------------
__global__ __launch_bounds__(256) void gemm_mfma(
    const unsigned short* __restrict__ Ap, const unsigned short* __restrict__ Bp,
    float* __restrict__ part)
{
    __shared__ unsigned short As[8192];   // [mtb(8)][ktb(2)][lane(64)][8]
    __shared__ unsigned short Bs[8192];

    const int t = threadIdx.x, l = t & 63, w = t >> 6;
    const int mtile = blockIdx.x, ntile = blockIdx.y, ks = blockIdx.z;
    const int wr = w >> 1, wc = w & 1;

    f32x4 acc[4][4] = {};

    int ktg = ks*(NKT/KSPLIT);            // 64 ktiles per split
    for (int step = 0; step < NSTEP; ++step, ktg += 2) {
        #pragma unroll
        for (int h = 0; h < 2; ++h) {
            int tb = 2*w + h;
            const unsigned short* ga =
                Ap + ((size_t)(mtile*8 + tb)*NKT + ktg)*512 + (size_t)l*8;
            gload16(ga,       &As[(tb*2 + 0)*512]);
            gload16(ga + 512, &As[(tb*2 + 1)*512]);
            const unsigned short* gb =
                Bp + ((size_t)(ntile*8 + tb)*NKT + ktg)*512 + (size_t)l*8;
            gload16(gb,       &Bs[(tb*2 + 0)*512]);
            gload16(gb + 512, &Bs[(tb*2 + 1)*512]);
        }
        __syncthreads();

        #pragma unroll
        for (int ktb = 0; ktb < 2; ++ktb) {
            short8 a[4], b[4];
            #pragma unroll
            for (int i = 0; i < 4; ++i)
                a[i] = *(const short8*)&As[(((wr*4 + i)*2 + ktb)*64 + l)*8];
            #pragma unroll
            for (int j = 0; j < 4; ++j)
                b[j] = *(const short8*)&Bs[(((wc*4 + j)*2 + ktb)*64 + l)*8];
            #pragma unroll
            for (int i = 0; i < 4; ++i)
                #pragma unroll
                for (int j = 0; j < 4; ++j)
                    acc[i][j] = __builtin_amdgcn_mfma_f32_16x16x32_bf16(
                        a[i], b[j], acc[i][j], 0, 0, 0);
        }
        __syncthreads();
    }

    // epilogue: C/D layout col = l&15, row = (l>>4)*4 + reg
    const int rbase = (l >> 4)*4, cl = l & 15;
    #pragma unroll
    for (int i = 0; i < 4; ++i) {
        #pragma unroll
        for (int j = 0; j < 4; ++j) {
            int m = mtile*128 + wr*64 + i*16 + rbase;
            int n = ntile*128 + wc*64 + j*16 + cl;
            float* p = part + ((size_t)ks*MPAD + m)*NPAD + n;
            #pragma unroll
            for (int r = 0; r < 4; ++r) p[(size_t)r*NPAD] = acc[i][j][r];
        }
    }
}

// ---------------------------------------------------------------------------
// build_spat: spat[b][fr][c] = history (fr<30) | sum of KSPLIT partials
// ---------------------------------------------------------------------------
__global__ __launch_bounds__(256) void build_spat(
    const float* __restrict__ hist, const float* __restrict__ part,
    float* __restrict__ spat)
{
    int idx = blockIdx.x*256 + threadIdx.x;
    if (idx >= BB*NFRM*CC) return;
    int c   = idx % CC;
    int rem = idx / CC;
    int fr  = rem % NFRM;
    int b   = rem / NFRM;
    float v;
    if (fr < NHIST) {
        v = hist[(b*NHIST + fr)*CC + c];
    } else {
        int m = b*NJIT + (fr - NHIST);
        v = 0.f;
        #pragma unroll
        for (int kp = 0; kp < KSPLIT; ++kp)
            v += part[((size_t)kp*MPAD + m)*NPAD + c];
    }
    spat[idx] = v;
}

// ---------------------------------------------------------------------------
// conv_loss: per (b,c) gather+upsample -> depthwise conv (chunked-8 rolling
// window, all-static register indexing) -> loss partial. One wave per block.
// ---------------------------------------------------------------------------
__global__ __launch_bounds__(64) void conv_loss(
    const float* __restrict__ spat, const int* __restrict__ sel,
    const float* __restrict__ wts,  const float* __restrict__ tc,
    const float* __restrict__ fb,   const float* __restrict__ spk,
    const float* __restrict__ tmask, float* __restrict__ lpart)
{
    __shared__ float tcs[256];
    __shared__ float ups[864];   // index t + (t>>3): conflict-free sliding window

    const int lane = threadIdx.x;
    const int c = blockIdx.x;
    const int b = blockIdx.y;

    for (int k = lane; k < 256; k += 64)
        tcs[k] = (k < KK) ? tc[c*KK + k] : 0.f;

    const float* spb = spat + (size_t)b*NFRM*CC + c;
    for (int tt = lane; tt < 768; tt += 64) {
        float v = 0.f;
        if (tt < NBINS) {
            int base = (b*NBINS + tt)*2;
            int s0 = sel[base], s1 = sel[base+1];
            float w0 = wts[base], w1 = wts[base+1];
            v = w0 * spb[s0*CC] + w1 * spb[s1*CC];
        }
        ups[tt + (tt >> 3)] = v;
    }
    __syncthreads();

    const int t0 = lane * 8;
    float u[16];
    #pragma unroll
    for (int j = 0; j < 16; ++j) { int q = t0 + j; u[j] = ups[q + (q >> 3)]; }

    float acc[8] = {};
    #pragma unroll 4
    for (int kc = 0; kc < 248; kc += 8) {
        #pragma unroll
        for (int kk = 0; kk < 8; ++kk) {
            float w = tcs[kc + kk];
            #pragma unroll
            for (int j = 0; j < 8; ++j) acc[j] += w * u[kk + j];
        }
        #pragma unroll
        for (int j = 0; j < 8; ++j) u[j] = u[j + 8];
        #pragma unroll
        for (int j = 0; j < 8; ++j) {
            int q = t0 + kc + 16 + j;
            u[j + 8] = ups[q + (q >> 3)];
        }
    }
    #pragma unroll
    for (int kk = 0; kk < 8; ++kk) {
        float w = tcs[248 + kk];
        #pragma unroll
        for (int j = 0; j < 8; ++j) acc[j] += w * u[kk + j];
    }

    const size_t bc = (size_t)b*CC + c;
    const float* fbp = fb  + bc*(TOUT+1);
    const float* sp  = spk + bc*NBINS + KK;
    const float* tm  = tmask + (size_t)b*TOUT;
    float lsum = 0.f;
    #pragma unroll
    for (int j = 0; j < 8; ++j) {
        int tt = t0 + j;
        if (tt < TOUT) {
            float g  = acc[j] + fbp[tt];
            float sv = sp[tt];
            lsum += (__expf(g) - sv*g) * tm[tt];
        }
    }
    #pragma unroll
    for (int off = 32; off > 0; off >>= 1)
        lsum += __shfl_down(lsum, off);
    if (lane == 0) lpart[bc] = lsum * MAGIC;
}

__global__ __launch_bounds__(256) void reduce_out(
    const float* __restrict__ lpart, float* __restrict__ out)
{
    __shared__ float red[256];
    int b = blockIdx.x, t = threadIdx.x;
    float s = 0.f;
    for (int i = t; i < CC; i += 256) s += lpart[(size_t)b*CC + i];
    red[t] = s; __syncthreads();
    for (int o = 128; o > 0; o >>= 1) {
        if (t < o) red[t] += red[t+o];
        __syncthreads();
    }
    if (t == 0) out[b] = red[0];
}

extern "C" void kernel_launch(void* const* d_in, const int* in_sizes, int n_in,
                              void* d_out, int out_size, void* d_ws, size_t ws_size,
                              hipStream_t stream) {
    const float* image = (const float*)d_in[0];
    const float* spk   = (const float*)d_in[1];
    const int*   eye   = (const int*)d_in[2];
    const float* tmask = (const float*)d_in[3];
    const int*   sel   = (const int*)d_in[4];
    const float* wts   = (const float*)d_in[5];
    const float* filt  = (const float*)d_in[6];
    const float* tc    = (const float*)d_in[7];
    const float* fb    = (const float*)d_in[8];
    const float* hist  = (const float*)d_in[9];
    float* out = (float*)d_out;

    unsigned short* Ap = (unsigned short*)d_ws;                 // 512*40960 bf16
    unsigned short* Bp = Ap + (size_t)MPAD*PP;                  // 768*40960 bf16
    float* part  = (float*)(Bp + (size_t)NPAD*PP);              // 20*512*768 f32
    float* spat  = part + (size_t)KSPLIT*MPAD*NPAD;             // 8*90*700 f32
    float* lpart = spat + (size_t)BB*NFRM*CC;                   // 8*700 f32

    pack_a_k <<<dim3(PACKA_BLKS), 256, 0, stream>>>(image, eye, Ap);
    pack_b_k <<<dim3(48*80), 256, 0, stream>>>(filt, Bp);
    gemm_mfma<<<dim3(4, 6, KSPLIT), 256, 0, stream>>>(Ap, Bp, part);
    build_spat<<<dim3((BB*NFRM*CC + 255)/256), 256, 0, stream>>>(hist, part, spat);
    conv_loss<<<dim3(CC, BB), 64, 0, stream>>>(spat, sel, wts, tc, fb, spk, tmask, lpart);
    reduce_out<<<dim3(BB), 256, 0, stream>>>(lpart, out);
}

// Round 5
// 152.919 us; speedup vs baseline: 1.0638x; 1.0638x over previous
//
#include <hip/hip_runtime.h>
#include <hip/hip_bf16.h>
#include <math.h>

// Problem constants
#define BB    8
#define HH    160
#define WW    256
#define CC    700
#define KK    250
#define NBINS 750
#define NHIST 30
#define NJIT  60
#define NFRM  90
#define PP    (HH*WW)      // 40960
#define TOUT  500
#define MAGIC (400.0f/750.0f)

// Padded GEMM dims
#define MPAD  512          // 480 -> 512 (32 tiles of 16)
#define NPAD  768          // 700 -> 768 (48 tiles of 16)
#define NKT   1280         // K / 32
#define KSPLIT 20
#define NSTEP 32           // 64 ktiles per split / 2 per BK=64 step
#define PACKA2_BLKS (32*80)   // 2560: mt(32) x 512px-supertile(80)
#define PACKB2_BLKS (48*80)   // 3840

typedef __attribute__((ext_vector_type(8))) short short8;
typedef __attribute__((ext_vector_type(4))) short short4v;
typedef __attribute__((ext_vector_type(4))) float f32x4;

__device__ __forceinline__ unsigned short f2bf(float x) {
    unsigned u = __builtin_bit_cast(unsigned, x);
    u += 0x7fffu + ((u >> 16) & 1u);   // RNE
    return (unsigned short)(u >> 16);
}

__device__ __forceinline__ void gload16(const void* g, void* l) {
    __builtin_amdgcn_global_load_lds(
        (const __attribute__((address_space(1))) unsigned int*)g,
        (__attribute__((address_space(3))) unsigned int*)l, 16, 0, 0);
}

// LDS byte-offset swizzle (involution, touches bank bits 4-6 only)
__device__ __forceinline__ int SWZ(int X) { return X ^ (((X >> 8) & 7) << 4); }

// ---------------------------------------------------------------------------
// pack_ab2: both operands -> fragment-ready bf16 via LDS transpose.
// Block = 16 rows x 512 k. All global reads coalesced (A: one wave reads one
// jittered row segment = contiguous image floats; B: contiguous filter row).
// LDS staged in fragment layout (SWZ keeps writes at the 2/bank b16 floor and
// the b128 readback at the uniform 8/bank floor). Output: 16KB coalesced.
// Fragment byte offset within tile: X(r,pl) = (pl>>5)*1024 + ((pl>>3)&3)*256
//                                            + r*16 + (pl&7)*2
// ---------------------------------------------------------------------------
__global__ __launch_bounds__(256) void pack_ab2(
    const float* __restrict__ img, const int* __restrict__ eye,
    const float* __restrict__ filt,
    unsigned short* __restrict__ Ap, unsigned short* __restrict__ Bp)
{
    __shared__ unsigned short lds[8192];   // 16KB
    const int t = threadIdx.x, l = t & 63, w = t >> 6;
    const int bid = blockIdx.x;

    if (bid < PACKA2_BLKS) {
        // ----- A: jittered image -----
        const int mt    = bid / 80;            // 0..31
        const int kt0   = (bid % 80) * 16;     // ktile base
        const int kbase = kt0 * 32;            // pixel base (mult of 512)

        #pragma unroll
        for (int sub = 0; sub < 4; ++sub) {
            int r = sub*4 + w;                 // 0..15
            int m = mt*16 + r;
            int b = 0, dy = 0, dx = 0;
            bool mok = (m < 480);
            if (mok) {
                b = m / 60; int f = m % 60;
                dy = eye[(b*NJIT + f)*2 + 0];
                dx = eye[(b*NJIT + f)*2 + 1];
            }
            const float* imgb = img + (size_t)b*PP;
            #pragma unroll
            for (int h = 0; h < 2; ++h) {
                int ir = (kbase >> 8) + h + dy;
                bool rok = mok && (ir < HH);
                #pragma unroll
                for (int q = 0; q < 4; ++q) {
                    int cc = q*64 + l + dx;
                    float v = 0.f;
                    if (rok && cc < WW) v = imgb[ir*WW + cc];   // coalesced
                    int pl = h*256 + q*64 + l;
                    int X = ((pl>>5)<<10) | (((pl>>3)&3)<<8) | (r<<4) | ((pl&7)<<1);
                    *(unsigned short*)((char*)lds + SWZ(X)) = f2bf(v);
                }
            }
        }
        __syncthreads();

        unsigned short* outp = Ap + ((size_t)mt*NKT + kt0)*512;
        #pragma unroll
        for (int i = 0; i < 4; ++i) {
            int X = i*4096 + t*16;             // 1KB/wave contiguous stores
            short8 v = *(const short8*)((const char*)lds + SWZ(X));
            *(short8*)((char*)outp + X) = v;
        }
    } else {
        // ----- B: filters -----
        const int bb    = bid - PACKA2_BLKS;
        const int nt    = bb / 80;             // 0..47
        const int kt0   = (bb % 80) * 16;
        const int kbase = kt0 * 32;

        #pragma unroll
        for (int sub = 0; sub < 4; ++sub) {
            int r = sub*4 + w;
            int n = nt*16 + r;
            float4 va = make_float4(0.f,0.f,0.f,0.f), vb = va;
            if (n < CC) {
                const float* row = filt + (size_t)n*PP + kbase;
                va = *(const float4*)(row + l*4);
                vb = *(const float4*)(row + l*4 + 256);
            }
            short4v pa, pb;
            pa[0]=(short)f2bf(va.x); pa[1]=(short)f2bf(va.y);
            pa[2]=(short)f2bf(va.z); pa[3]=(short)f2bf(va.w);
            pb[0]=(short)f2bf(vb.x); pb[1]=(short)f2bf(vb.y);
            pb[2]=(short)f2bf(vb.z); pb[3]=(short)f2bf(vb.w);
            int k0a = l*4, k0b = l*4 + 256;
            int Xa = ((k0a>>5)<<10) | (((k0a>>3)&3)<<8) | (r<<4) | ((k0a&7)<<1);
            int Xb = ((k0b>>5)<<10) | (((k0b>>3)&3)<<8) | (r<<4) | ((k0b&7)<<1);
            *(short4v*)((char*)lds + SWZ(Xa)) = pa;
            *(short4v*)((char*)lds + SWZ(Xb)) = pb;
        }
        __syncthreads();

        unsigned short* outp = Bp + ((size_t)nt*NKT + kt0)*512;
        #pragma unroll
        for (int i = 0; i < 4; ++i) {
            int X = i*4096 + t*16;
            short8 v = *(const short8*)((const char*)lds + SWZ(X));
            *(short8*)((char*)outp + X) = v;
        }
    }
}

// ---------------------------------------------------------------------------
// gemm_mfma: bf16 MFMA 16x16x32. BM=BN=128, BK=64, 4 waves (2x2), each a
// 64x64 sub-tile (4x4 frags). grid (4, 6, KSPLIT) = 480 blocks.
// ---------------------------------------------------------------------------
__global__ __launch_bounds__(256) void gemm_mfma(
    const unsigned short* __restrict__ Ap, const unsigned short* __restrict__ Bp,
    float* __restrict__ part)
{
    __shared__ unsigned short As[8192];   // [mtb(8)][ktb(2)][lane(64)][8]
    __shared__ unsigned short Bs[8192];

    const int t = threadIdx.x, l = t & 63, w = t >> 6;
    const int mtile = blockIdx.x, ntile = blockIdx.y, ks = blockIdx.z;
    const int wr = w >> 1, wc = w & 1;

    f32x4 acc[4][4] = {};

    int ktg = ks*(NKT/KSPLIT);            // 64 ktiles per split
    for (int step = 0; step < NSTEP; ++step, ktg += 2) {
        #pragma unroll
        for (int h = 0; h < 2; ++h) {
            int tb = 2*w + h;
            const unsigned short* ga =
                Ap + ((size_t)(mtile*8 + tb)*NKT + ktg)*512 + (size_t)l*8;
            gload16(ga,       &As[(tb*2 + 0)*512]);
            gload16(ga + 512, &As[(tb*2 + 1)*512]);
            const unsigned short* gb =
                Bp + ((size_t)(ntile*8 + tb)*NKT + ktg)*512 + (size_t)l*8;
            gload16(gb,       &Bs[(tb*2 + 0)*512]);
            gload16(gb + 512, &Bs[(tb*2 + 1)*512]);
        }
        __syncthreads();

        #pragma unroll
        for (int ktb = 0; ktb < 2; ++ktb) {
            short8 a[4], b[4];
            #pragma unroll
            for (int i = 0; i < 4; ++i)
                a[i] = *(const short8*)&As[(((wr*4 + i)*2 + ktb)*64 + l)*8];
            #pragma unroll
            for (int j = 0; j < 4; ++j)
                b[j] = *(const short8*)&Bs[(((wc*4 + j)*2 + ktb)*64 + l)*8];
            #pragma unroll
            for (int i = 0; i < 4; ++i)
                #pragma unroll
                for (int j = 0; j < 4; ++j)
                    acc[i][j] = __builtin_amdgcn_mfma_f32_16x16x32_bf16(
                        a[i], b[j], acc[i][j], 0, 0, 0);
        }
        __syncthreads();
    }

    // epilogue: C/D layout col = l&15, row = (l>>4)*4 + reg
    const int rbase = (l >> 4)*4, cl = l & 15;
    #pragma unroll
    for (int i = 0; i < 4; ++i) {
        #pragma unroll
        for (int j = 0; j < 4; ++j) {
            int m = mtile*128 + wr*64 + i*16 + rbase;
            int n = ntile*128 + wc*64 + j*16 + cl;
            float* p = part + ((size_t)ks*MPAD + m)*NPAD + n;
            #pragma unroll
            for (int r = 0; r < 4; ++r) p[(size_t)r*NPAD] = acc[i][j][r];
        }
    }
}

// ---------------------------------------------------------------------------
// build_spat: spat[b][fr][c] = history (fr<30) | sum of KSPLIT partials
// ---------------------------------------------------------------------------
__global__ __launch_bounds__(256) void build_spat(
    const float* __restrict__ hist, const float* __restrict__ part,
    float* __restrict__ spat)
{
    int idx = blockIdx.x*256 + threadIdx.x;
    if (idx >= BB*NFRM*CC) return;
    int c   = idx % CC;
    int rem = idx / CC;
    int fr  = rem % NFRM;
    int b   = rem / NFRM;
    float v;
    if (fr < NHIST) {
        v = hist[(b*NHIST + fr)*CC + c];
    } else {
        int m = b*NJIT + (fr - NHIST);
        v = 0.f;
        #pragma unroll
        for (int kp = 0; kp < KSPLIT; ++kp)
            v += part[((size_t)kp*MPAD + m)*NPAD + c];
    }
    spat[idx] = v;
}

// ---------------------------------------------------------------------------
// conv_loss: per (b,c) gather+upsample -> depthwise conv (chunked-8 rolling
// window, all-static register indexing) -> loss partial. One wave per block.
// ---------------------------------------------------------------------------
__global__ __launch_bounds__(64) void conv_loss(
    const float* __restrict__ spat, const int* __restrict__ sel,
    const float* __restrict__ wts,  const float* __restrict__ tc,
    const float* __restrict__ fb,   const float* __restrict__ spk,
    const float* __restrict__ tmask, float* __restrict__ lpart)
{
    __shared__ float tcs[256];
    __shared__ float ups[864];   // index t + (t>>3): conflict-free sliding window

    const int lane = threadIdx.x;
    const int c = blockIdx.x;
    const int b = blockIdx.y;

    for (int k = lane; k < 256; k += 64)
        tcs[k] = (k < KK) ? tc[c*KK + k] : 0.f;

    const float* spb = spat + (size_t)b*NFRM*CC + c;
    for (int tt = lane; tt < 768; tt += 64) {
        float v = 0.f;
        if (tt < NBINS) {
            int base = (b*NBINS + tt)*2;
            int s0 = sel[base], s1 = sel[base+1];
            float w0 = wts[base], w1 = wts[base+1];
            v = w0 * spb[s0*CC] + w1 * spb[s1*CC];
        }
        ups[tt + (tt >> 3)] = v;
    }
    __syncthreads();

    const int t0 = lane * 8;
    float u[16];
    #pragma unroll
    for (int j = 0; j < 16; ++j) { int q = t0 + j; u[j] = ups[q + (q >> 3)]; }

    float acc[8] = {};
    #pragma unroll 4
    for (int kc = 0; kc < 248; kc += 8) {
        #pragma unroll
        for (int kk = 0; kk < 8; ++kk) {
            float w = tcs[kc + kk];
            #pragma unroll
            for (int j = 0; j < 8; ++j) acc[j] += w * u[kk + j];
        }
        #pragma unroll
        for (int j = 0; j < 8; ++j) u[j] = u[j + 8];
        #pragma unroll
        for (int j = 0; j < 8; ++j) {
            int q = t0 + kc + 16 + j;
            u[j + 8] = ups[q + (q >> 3)];
        }
    }
    #pragma unroll
    for (int kk = 0; kk < 8; ++kk) {
        float w = tcs[248 + kk];
        #pragma unroll
        for (int j = 0; j < 8; ++j) acc[j] += w * u[kk + j];
    }

    const size_t bc = (size_t)b*CC + c;
    const float* fbp = fb  + bc*(TOUT+1);
    const float* sp  = spk + bc*NBINS + KK;
    const float* tm  = tmask + (size_t)b*TOUT;
    float lsum = 0.f;
    #pragma unroll
    for (int j = 0; j < 8; ++j) {
        int tt = t0 + j;
        if (tt < TOUT) {
            float g  = acc[j] + fbp[tt];
            float sv = sp[tt];
            lsum += (__expf(g) - sv*g) * tm[tt];
        }
    }
    #pragma unroll
    for (int off = 32; off > 0; off >>= 1)
        lsum += __shfl_down(lsum, off);
    if (lane == 0) lpart[bc] = lsum * MAGIC;
}

__global__ __launch_bounds__(256) void reduce_out(
    const float* __restrict__ lpart, float* __restrict__ out)
{
    __shared__ float red[256];
    int b = blockIdx.x, t = threadIdx.x;
    float s = 0.f;
    for (int i = t; i < CC; i += 256) s += lpart[(size_t)b*CC + i];
    red[t] = s; __syncthreads();
    for (int o = 128; o > 0; o >>= 1) {
        if (t < o) red[t] += red[t+o];
        __syncthreads();
    }
    if (t == 0) out[b] = red[0];
}

extern "C" void kernel_launch(void* const* d_in, const int* in_sizes, int n_in,
                              void* d_out, int out_size, void* d_ws, size_t ws_size,
                              hipStream_t stream) {
    const float* image = (const float*)d_in[0];
    const float* spk   = (const float*)d_in[1];
    const int*   eye   = (const int*)d_in[2];
    const float* tmask = (const float*)d_in[3];
    const int*   sel   = (const int*)d_in[4];
    const float* wts   = (const float*)d_in[5];
    const float* filt  = (const float*)d_in[6];
    const float* tc    = (const float*)d_in[7];
    const float* fb    = (const float*)d_in[8];
    const float* hist  = (const float*)d_in[9];
    float* out = (float*)d_out;

    unsigned short* Ap = (unsigned short*)d_ws;                 // 512*40960 bf16
    unsigned short* Bp = Ap + (size_t)MPAD*PP;                  // 768*40960 bf16
    float* part  = (float*)(Bp + (size_t)NPAD*PP);              // 20*512*768 f32
    float* spat  = part + (size_t)KSPLIT*MPAD*NPAD;             // 8*90*700 f32
    float* lpart = spat + (size_t)BB*NFRM*CC;                   // 8*700 f32

    pack_ab2 <<<dim3(PACKA2_BLKS + PACKB2_BLKS), 256, 0, stream>>>(image, eye, filt, Ap, Bp);
    gemm_mfma<<<dim3(4, 6, KSPLIT), 256, 0, stream>>>(Ap, Bp, part);
    build_spat<<<dim3((BB*NFRM*CC + 255)/256), 256, 0, stream>>>(hist, part, spat);
    conv_loss<<<dim3(CC, BB), 64, 0, stream>>>(spat, sel, wts, tc, fb, spk, tmask, lpart);
    reduce_out<<<dim3(BB), 256, 0, stream>>>(lpart, out);
}

// Round 6
// 152.477 us; speedup vs baseline: 1.0669x; 1.0029x over previous
//
#include <hip/hip_runtime.h>
#include <hip/hip_bf16.h>
#include <math.h>

// Problem constants
#define BB    8
#define HH    160
#define WW    256
#define CC    700
#define KK    250
#define NBINS 750
#define NHIST 30
#define NJIT  60
#define NFRM  90
#define PP    (HH*WW)      // 40960
#define TOUT  500
#define MAGIC (400.0f/750.0f)

// GEMM dims
#define MPAD  512          // 480 -> 512 (32 tiles of 16)
#define NPAD  768          // 700 -> 768
#define NKT   1280         // K / 32
#define KSPLIT 40
#define ZKT   32           // kt per z-slice (1024 px)
#define NSTEP 16           // 1024 px / 64 per step
#define PACKA2_BLKS (32*80)   // 2560

typedef __attribute__((ext_vector_type(8))) short short8;
typedef __attribute__((ext_vector_type(4))) float f32x4;

__device__ __forceinline__ unsigned short f2bf(float x) {
    unsigned u = __builtin_bit_cast(unsigned, x);
    u += 0x7fffu + ((u >> 16) & 1u);   // RNE
    return (unsigned short)(u >> 16);
}

__device__ __forceinline__ void gload16(const void* g, void* l) {
    __builtin_amdgcn_global_load_lds(
        (const __attribute__((address_space(1))) unsigned int*)g,
        (__attribute__((address_space(3))) unsigned int*)l, 16, 0, 0);
}

// LDS byte-offset swizzle for pack_a staging (involution, bank bits 4-6)
__device__ __forceinline__ int SWZ(int X) { return X ^ (((X >> 8) & 7) << 4); }

// ---------------------------------------------------------------------------
// pack_a: jittered image -> bf16 fragment-ready layout via LDS transpose.
// Block = 16 m-rows x 512 px. Reads coalesced (contiguous image row segments).
// Ap[((mt*1280 + kt)*64 + l)*8 + j] = A[mt*16 + (l&15)][kt*32 + 8*(l>>4) + j]
// ---------------------------------------------------------------------------
__global__ __launch_bounds__(256) void pack_a(
    const float* __restrict__ img, const int* __restrict__ eye,
    unsigned short* __restrict__ Ap)
{
    __shared__ unsigned short lds[8192];   // 16KB
    const int t = threadIdx.x, w = t >> 6, l = t & 63;
    const int mt    = blockIdx.x / 80;            // 0..31
    const int kt0   = (blockIdx.x % 80) * 16;     // ktile base
    const int kbase = kt0 * 32;                   // pixel base (mult of 512)

    #pragma unroll
    for (int sub = 0; sub < 4; ++sub) {
        int r = sub*4 + w;                 // 0..15
        int m = mt*16 + r;
        int b = 0, dy = 0, dx = 0;
        bool mok = (m < 480);
        if (mok) {
            b = m / 60; int f = m % 60;
            dy = eye[(b*NJIT + f)*2 + 0];
            dx = eye[(b*NJIT + f)*2 + 1];
        }
        const float* imgb = img + (size_t)b*PP;
        #pragma unroll
        for (int h = 0; h < 2; ++h) {
            int ir = (kbase >> 8) + h + dy;
            bool rok = mok && (ir < HH);
            #pragma unroll
            for (int q = 0; q < 4; ++q) {
                int cc = q*64 + l + dx;
                float v = 0.f;
                if (rok && cc < WW) v = imgb[ir*WW + cc];   // coalesced
                int pl = h*256 + q*64 + l;
                int X = ((pl>>5)<<10) | (((pl>>3)&3)<<8) | (r<<4) | ((pl&7)<<1);
                *(unsigned short*)((char*)lds + SWZ(X)) = f2bf(v);
            }
        }
    }
    __syncthreads();

    unsigned short* outp = Ap + ((size_t)mt*NKT + kt0)*512;
    #pragma unroll
    for (int i = 0; i < 4; ++i) {
        int X = i*4096 + t*16;             // 1KB/wave contiguous stores
        short8 v = *(const short8*)((const char*)lds + SWZ(X));
        *(short8*)((char*)outp + X) = v;
    }
}

// ---------------------------------------------------------------------------
// gemm_bf: C += A(bf16, packed) x B(fp32 filt, converted inline).
// BM=256, BN=128, BK=64. 8 waves (512 thr), each a 64x64 sub-tile.
// grid (2 mtiles, 6 ntiles, KSPLIT=40). B is read fp32 ONCE per mtile (2x
// total) and converted in-register -> fragment-layout LDS; Bp never exists.
// Bs layout byte-offset: X(row,pl) = (row>>4)<<11 | (pl>>5)<<10 |
//      ((pl>>3)&3)<<8 | (row&15)<<4 | (pl&7)<<1   (row=n within 128, pl=k
//      within 64). Writes & reads both at the 8-dword/bank b128 floor.
// ---------------------------------------------------------------------------
__global__ __launch_bounds__(512) void gemm_bf(
    const unsigned short* __restrict__ Ap, const float* __restrict__ filt,
    float* __restrict__ part)
{
    __shared__ unsigned short As[16384];  // 32KB: [tb(16)][ktb(2)][lane][8]
    __shared__ unsigned short Bs[8192];   // 16KB: fragment layout (X above)

    const int t = threadIdx.x, l = t & 63, w = t >> 6;
    const int mtile = blockIdx.x, ntile = blockIdx.y, z = blockIdx.z;
    const int wr = w >> 1, wc = w & 1;
    const int n0 = ntile*128;

    // B staging assignment: thread -> row (t>>2) in [0,128), px chunk (t&3)*16
    const int brow = t >> 2;
    const int bn   = n0 + brow;
    const bool bok = bn < CC;
    const int bpx  = (t & 3) * 16;
    const float* browp = filt + (size_t)(bok ? bn : 0)*PP + bpx;
    // two 16B LDS writes at pl = bpx and bpx+8
    const int pl0 = bpx, pl1 = bpx + 8;
    const int X0 = ((brow>>4)<<11) | ((pl0>>5)<<10) | (((pl0>>3)&3)<<8) | ((brow&15)<<4);
    const int X1 = ((brow>>4)<<11) | ((pl1>>5)<<10) | (((pl1>>3)&3)<<8) | ((brow&15)<<4);

    f32x4 acc[4][4] = {};

    int ktg = z*ZKT;
    for (int step = 0; step < NSTEP; ++step, ktg += 2) {
        const int kb = ktg*32;
        // ---- B: fp32 global -> regs (issue before A so latency overlaps)
        float4 v0 = make_float4(0.f,0.f,0.f,0.f), v1 = v0, v2 = v0, v3 = v0;
        if (bok) {
            v0 = *(const float4*)(browp + kb);
            v1 = *(const float4*)(browp + kb + 4);
            v2 = *(const float4*)(browp + kb + 8);
            v3 = *(const float4*)(browp + kb + 12);
        }
        // ---- A: async global->LDS (packed, linear)
        #pragma unroll
        for (int h = 0; h < 2; ++h) {
            int tb = 2*w + h;             // 0..15
            const unsigned short* ga =
                Ap + ((size_t)(mtile*16 + tb)*NKT + ktg)*512 + (size_t)l*8;
            gload16(ga,       &As[(tb*2 + 0)*512]);
            gload16(ga + 512, &As[(tb*2 + 1)*512]);
        }
        // ---- B: convert + fragment-layout LDS write (2 x b128)
        {
            short8 p0, p1;
            p0[0]=(short)f2bf(v0.x); p0[1]=(short)f2bf(v0.y);
            p0[2]=(short)f2bf(v0.z); p0[3]=(short)f2bf(v0.w);
            p0[4]=(short)f2bf(v1.x); p0[5]=(short)f2bf(v1.y);
            p0[6]=(short)f2bf(v1.z); p0[7]=(short)f2bf(v1.w);
            p1[0]=(short)f2bf(v2.x); p1[1]=(short)f2bf(v2.y);
            p1[2]=(short)f2bf(v2.z); p1[3]=(short)f2bf(v2.w);
            p1[4]=(short)f2bf(v3.x); p1[5]=(short)f2bf(v3.y);
            p1[6]=(short)f2bf(v3.z); p1[7]=(short)f2bf(v3.w);
            *(short8*)((char*)Bs + X0) = p0;
            *(short8*)((char*)Bs + X1) = p1;
        }
        __syncthreads();

        #pragma unroll
        for (int ktb = 0; ktb < 2; ++ktb) {
            short8 a[4], b[4];
            #pragma unroll
            for (int i = 0; i < 4; ++i)
                a[i] = *(const short8*)&As[(((wr*4 + i)*2 + ktb)*64 + l)*8];
            #pragma unroll
            for (int j = 0; j < 4; ++j) {
                int Xr = ((wc*4 + j)<<11) | (ktb<<10) | ((l>>4)<<8) | ((l&15)<<4);
                b[j] = *(const short8*)((const char*)Bs + Xr);
            }
            #pragma unroll
            for (int i = 0; i < 4; ++i)
                #pragma unroll
                for (int j = 0; j < 4; ++j)
                    acc[i][j] = __builtin_amdgcn_mfma_f32_16x16x32_bf16(
                        a[i], b[j], acc[i][j], 0, 0, 0);
        }
        __syncthreads();
    }

    // epilogue: C/D layout col = l&15, row = (l>>4)*4 + reg
    const int rbase = (l >> 4)*4, cl = l & 15;
    #pragma unroll
    for (int i = 0; i < 4; ++i) {
        #pragma unroll
        for (int j = 0; j < 4; ++j) {
            int m = mtile*256 + wr*64 + i*16 + rbase;
            int n = ntile*128 + wc*64 + j*16 + cl;
            float* p = part + ((size_t)z*MPAD + m)*NPAD + n;
            #pragma unroll
            for (int r = 0; r < 4; ++r) p[(size_t)r*NPAD] = acc[i][j][r];
        }
    }
}

// ---------------------------------------------------------------------------
// build_spat: spat[b][fr][c] = history (fr<30) | sum of KSPLIT partials
// ---------------------------------------------------------------------------
__global__ __launch_bounds__(256) void build_spat(
    const float* __restrict__ hist, const float* __restrict__ part,
    float* __restrict__ spat)
{
    int idx = blockIdx.x*256 + threadIdx.x;
    if (idx >= BB*NFRM*CC) return;
    int c   = idx % CC;
    int rem = idx / CC;
    int fr  = rem % NFRM;
    int b   = rem / NFRM;
    float v;
    if (fr < NHIST) {
        v = hist[(b*NHIST + fr)*CC + c];
    } else {
        int m = b*NJIT + (fr - NHIST);
        v = 0.f;
        #pragma unroll
        for (int kp = 0; kp < KSPLIT; ++kp)
            v += part[((size_t)kp*MPAD + m)*NPAD + c];
    }
    spat[idx] = v;
}

// ---------------------------------------------------------------------------
// conv_loss: per (b,c) gather+upsample -> depthwise conv (chunked-8 rolling
// window, all-static register indexing) -> loss partial. One wave per block.
// ---------------------------------------------------------------------------
__global__ __launch_bounds__(64) void conv_loss(
    const float* __restrict__ spat, const int* __restrict__ sel,
    const float* __restrict__ wts,  const float* __restrict__ tc,
    const float* __restrict__ fb,   const float* __restrict__ spk,
    const float* __restrict__ tmask, float* __restrict__ lpart)
{
    __shared__ float tcs[256];
    __shared__ float ups[864];   // index t + (t>>3): conflict-free sliding window

    const int lane = threadIdx.x;
    const int c = blockIdx.x;
    const int b = blockIdx.y;

    for (int k = lane; k < 256; k += 64)
        tcs[k] = (k < KK) ? tc[c*KK + k] : 0.f;

    const float* spb = spat + (size_t)b*NFRM*CC + c;
    for (int tt = lane; tt < 768; tt += 64) {
        float v = 0.f;
        if (tt < NBINS) {
            int base = (b*NBINS + tt)*2;
            int s0 = sel[base], s1 = sel[base+1];
            float w0 = wts[base], w1 = wts[base+1];
            v = w0 * spb[s0*CC] + w1 * spb[s1*CC];
        }
        ups[tt + (tt >> 3)] = v;
    }
    __syncthreads();

    const int t0 = lane * 8;
    float u[16];
    #pragma unroll
    for (int j = 0; j < 16; ++j) { int q = t0 + j; u[j] = ups[q + (q >> 3)]; }

    float acc[8] = {};
    #pragma unroll 4
    for (int kc = 0; kc < 248; kc += 8) {
        #pragma unroll
        for (int kk = 0; kk < 8; ++kk) {
            float w = tcs[kc + kk];
            #pragma unroll
            for (int j = 0; j < 8; ++j) acc[j] += w * u[kk + j];
        }
        #pragma unroll
        for (int j = 0; j < 8; ++j) u[j] = u[j + 8];
        #pragma unroll
        for (int j = 0; j < 8; ++j) {
            int q = t0 + kc + 16 + j;
            u[j + 8] = ups[q + (q >> 3)];
        }
    }
    #pragma unroll
    for (int kk = 0; kk < 8; ++kk) {
        float w = tcs[248 + kk];
        #pragma unroll
        for (int j = 0; j < 8; ++j) acc[j] += w * u[kk + j];
    }

    const size_t bc = (size_t)b*CC + c;
    const float* fbp = fb  + bc*(TOUT+1);
    const float* sp  = spk + bc*NBINS + KK;
    const float* tm  = tmask + (size_t)b*TOUT;
    float lsum = 0.f;
    #pragma unroll
    for (int j = 0; j < 8; ++j) {
        int tt = t0 + j;
        if (tt < TOUT) {
            float g  = acc[j] + fbp[tt];
            float sv = sp[tt];
            lsum += (__expf(g) - sv*g) * tm[tt];
        }
    }
    #pragma unroll
    for (int off = 32; off > 0; off >>= 1)
        lsum += __shfl_down(lsum, off);
    if (lane == 0) lpart[bc] = lsum * MAGIC;
}

__global__ __launch_bounds__(256) void reduce_out(
    const float* __restrict__ lpart, float* __restrict__ out)
{
    __shared__ float red[256];
    int b = blockIdx.x, t = threadIdx.x;
    float s = 0.f;
    for (int i = t; i < CC; i += 256) s += lpart[(size_t)b*CC + i];
    red[t] = s; __syncthreads();
    for (int o = 128; o > 0; o >>= 1) {
        if (t < o) red[t] += red[t+o];
        __syncthreads();
    }
    if (t == 0) out[b] = red[0];
}

extern "C" void kernel_launch(void* const* d_in, const int* in_sizes, int n_in,
                              void* d_out, int out_size, void* d_ws, size_t ws_size,
                              hipStream_t stream) {
    const float* image = (const float*)d_in[0];
    const float* spk   = (const float*)d_in[1];
    const int*   eye   = (const int*)d_in[2];
    const float* tmask = (const float*)d_in[3];
    const int*   sel   = (const int*)d_in[4];
    const float* wts   = (const float*)d_in[5];
    const float* filt  = (const float*)d_in[6];
    const float* tc    = (const float*)d_in[7];
    const float* fb    = (const float*)d_in[8];
    const float* hist  = (const float*)d_in[9];
    float* out = (float*)d_out;

    unsigned short* Ap = (unsigned short*)d_ws;                 // 512*40960 bf16
    float* part  = (float*)(Ap + (size_t)MPAD*PP);              // 40*512*768 f32
    float* spat  = part + (size_t)KSPLIT*MPAD*NPAD;             // 8*90*700 f32
    float* lpart = spat + (size_t)BB*NFRM*CC;                   // 8*700 f32

    pack_a   <<<dim3(PACKA2_BLKS), 256, 0, stream>>>(image, eye, Ap);
    gemm_bf  <<<dim3(2, 6, KSPLIT), 512, 0, stream>>>(Ap, filt, part);
    build_spat<<<dim3((BB*NFRM*CC + 255)/256), 256, 0, stream>>>(hist, part, spat);
    conv_loss<<<dim3(CC, BB), 64, 0, stream>>>(spat, sel, wts, tc, fb, spk, tmask, lpart);
    reduce_out<<<dim3(BB), 256, 0, stream>>>(lpart, out);
}

// Round 7
// 145.130 us; speedup vs baseline: 1.1209x; 1.0506x over previous
//
#include <hip/hip_runtime.h>
#include <hip/hip_bf16.h>
#include <math.h>

// Problem constants
#define BB    8
#define HH    160
#define WW    256
#define CC    700
#define KK    250
#define NBINS 750
#define NHIST 30
#define NJIT  60
#define NFRM  90
#define PP    (HH*WW)      // 40960
#define TOUT  500
#define MAGIC (400.0f/750.0f)

// GEMM dims
#define MPAD  512
#define NPAD  768
#define NKT   1280         // K / 32
#define KSPLIT 40          // z slices of 1024 px

typedef __attribute__((ext_vector_type(8))) short short8;
typedef __attribute__((ext_vector_type(4))) short short4v;
typedef __attribute__((ext_vector_type(4))) float f32x4;

__device__ __forceinline__ unsigned short f2bf(float x) {
    unsigned u = __builtin_bit_cast(unsigned, x);
    u += 0x7fffu + ((u >> 16) & 1u);   // RNE
    return (unsigned short)(u >> 16);
}

// LDS byte-offset swizzle for pack_a staging (involution, bank bits 4-6)
__device__ __forceinline__ int SWZ(int X) { return X ^ (((X >> 8) & 7) << 4); }

// ---------------------------------------------------------------------------
// pack_a: jittered image -> bf16 fragment-ready layout via LDS transpose.
// Block = 16 m-rows x 4x512 px (4 supertiles, eye data hoisted).
// Ap[((mt*1280 + kt)*64 + l)*8 + j] = A[mt*16 + (l&15)][kt*32 + 8*(l>>4) + j]
// ---------------------------------------------------------------------------
__global__ __launch_bounds__(256) void pack_a(
    const float* __restrict__ img, const int* __restrict__ eye,
    unsigned short* __restrict__ Ap)
{
    __shared__ unsigned short lds[8192];   // 16KB
    const int t = threadIdx.x, w = t >> 6, l = t & 63;
    const int mt = blockIdx.x;             // 0..31
    const int ch = blockIdx.y;             // 0..19

    int rb[4], rdy[4], rdx[4]; bool rvk[4];
    #pragma unroll
    for (int sub = 0; sub < 4; ++sub) {
        int r = sub*4 + w, m = mt*16 + r;
        rvk[sub] = (m < 480);
        int b = 0, dy = 0, dx = 0;
        if (rvk[sub]) {
            b = m / 60; int f = m % 60;
            dy = eye[(b*NJIT + f)*2 + 0];
            dx = eye[(b*NJIT + f)*2 + 1];
        }
        rb[sub] = b; rdy[sub] = dy; rdx[sub] = dx;
    }

    for (int q = 0; q < 4; ++q) {
        const int kt0   = (ch*4 + q)*16;
        const int kbase = kt0 * 32;
        #pragma unroll
        for (int sub = 0; sub < 4; ++sub) {
            int r = sub*4 + w;
            const float* imgb = img + (size_t)rb[sub]*PP;
            #pragma unroll
            for (int h = 0; h < 2; ++h) {
                int ir = (kbase >> 8) + h + rdy[sub];
                bool ok = rvk[sub] && (ir < HH);
                #pragma unroll
                for (int qq = 0; qq < 4; ++qq) {
                    int cc2 = qq*64 + l + rdx[sub];
                    float v = 0.f;
                    if (ok && cc2 < WW) v = imgb[ir*WW + cc2];   // coalesced
                    int pl = h*256 + qq*64 + l;
                    int X = ((pl>>5)<<10) | (((pl>>3)&3)<<8) | (r<<4) | ((pl&7)<<1);
                    *(unsigned short*)((char*)lds + SWZ(X)) = f2bf(v);
                }
            }
        }
        __syncthreads();
        unsigned short* outp = Ap + ((size_t)mt*NKT + kt0)*512;
        #pragma unroll
        for (int i = 0; i < 4; ++i) {
            int X = i*4096 + t*16;             // 1KB/wave contiguous stores
            short8 v = *(const short8*)((const char*)lds + SWZ(X));
            *(short8*)((char*)outp + X) = v;
        }
        __syncthreads();
    }
}

// ---------------------------------------------------------------------------
// gemm_bf: C += A(bf16 packed, direct per-wave frag loads) x B(fp32 filt,
// converted inline). BM=512 (full M -> B read ONCE), BN=128, BK=64.
// 8 waves (512 thr), wave (wr,wc) owns two 64x64 sub-tiles (h=0,1).
// grid = 240 blocks; bid -> (nt, z) with z%8 == bid%8 so the 6 blocks
// sharing one A z-slice land on one XCD's L2.
// Bs frag layout byte-offset: X(row,pl) = (row>>4)<<11 | (pl>>5)<<10 |
//      ((pl>>3)&3)<<8 | (row&15)<<4 | (pl&7)<<1
// ---------------------------------------------------------------------------
__global__ __launch_bounds__(512) void gemm_bf(
    const unsigned short* __restrict__ Ap, const float* __restrict__ filt,
    float* __restrict__ part)
{
    __shared__ unsigned short Bs[8192];   // 16KB: 128 rows x 64 k, frag layout

    const int t = threadIdx.x, l = t & 63, w = t >> 6;
    const int bid = blockIdx.x;
    const int z   = (bid & 7) + 8*((bid >> 3)/6);
    const int nt  = (bid >> 3) % 6;
    const int wr = w >> 1, wc = w & 1;
    const int n0 = nt*128;

    // B staging: thread t covers rows j*32 + (t>>4) at px0=(t&15)*4
    const int br  = t >> 4;
    const int px0 = (t & 15)*4;
    int wX[4]; bool wok[4]; const float* rp[4];
    #pragma unroll
    for (int j = 0; j < 4; ++j) {
        int row = j*32 + br;
        wok[j] = (n0 + row) < CC;
        rp[j]  = filt + (size_t)(n0 + row)*PP + z*1024 + px0;
        wX[j]  = ((row>>4)<<11) | ((px0>>5)<<10) | (((px0>>3)&3)<<8)
               | ((row&15)<<4) | ((px0&7)<<1);
    }

    f32x4 acc[2][4][4] = {};

    // prologue: stage Bs(0)
    float4 bv[4];
    #pragma unroll
    for (int j = 0; j < 4; ++j)
        bv[j] = wok[j] ? *(const float4*)(rp[j]) : make_float4(0.f,0.f,0.f,0.f);
    #pragma unroll
    for (int j = 0; j < 4; ++j) {
        short4v p; p[0]=(short)f2bf(bv[j].x); p[1]=(short)f2bf(bv[j].y);
        p[2]=(short)f2bf(bv[j].z); p[3]=(short)f2bf(bv[j].w);
        *(short4v*)((char*)Bs + wX[j]) = p;
    }

    const size_t kt00 = (size_t)z*32;
    for (int step = 0; step < 16; ++step) {
        __syncthreads();               // Bs(step) visible
        short8 breg[2][4];
        #pragma unroll
        for (int ktb = 0; ktb < 2; ++ktb)
            #pragma unroll
            for (int j = 0; j < 4; ++j) {
                int Xr = ((wc*4 + j)<<11) | (ktb<<10) | ((l>>4)<<8) | ((l&15)<<4);
                breg[ktb][j] = *(const short8*)((const char*)Bs + Xr);
            }
        // next-step B (issued now, naturally drained at the step-end barrier)
        if (step < 15) {
            #pragma unroll
            for (int j = 0; j < 4; ++j)
                bv[j] = wok[j] ? *(const float4*)(rp[j] + (step+1)*64)
                               : make_float4(0.f,0.f,0.f,0.f);
        }
        // A frags: direct global loads (packed layout == frag layout),
        // one-deep prefetch across the 8 (h,i) sub-tiles.
        const unsigned short* ab = Ap + (kt00 + step*2)*512 + (size_t)l*8;
        const size_t TS = (size_t)NKT*512;   // tile stride in shorts
        short8 p0 = *(const short8*)(ab + (size_t)(wr*4)*TS);
        short8 p1 = *(const short8*)(ab + (size_t)(wr*4)*TS + 512);
        #pragma unroll
        for (int h = 0; h < 2; ++h)
            #pragma unroll
            for (int i = 0; i < 4; ++i) {
                short8 va0 = p0, va1 = p1;
                int hi = h*4 + i;
                if (hi < 7) {
                    int hn = (hi+1) >> 2, in = (hi+1) & 3;
                    const unsigned short* an = ab + (size_t)(hn*16 + wr*4 + in)*TS;
                    p0 = *(const short8*)(an);
                    p1 = *(const short8*)(an + 512);
                }
                #pragma unroll
                for (int j = 0; j < 4; ++j) {
                    acc[h][i][j] = __builtin_amdgcn_mfma_f32_16x16x32_bf16(
                        va0, breg[0][j], acc[h][i][j], 0, 0, 0);
                    acc[h][i][j] = __builtin_amdgcn_mfma_f32_16x16x32_bf16(
                        va1, breg[1][j], acc[h][i][j], 0, 0, 0);
                }
            }
        __syncthreads();               // breg reads done -> Bs writable
        if (step < 15) {
            #pragma unroll
            for (int j = 0; j < 4; ++j) {
                short4v p; p[0]=(short)f2bf(bv[j].x); p[1]=(short)f2bf(bv[j].y);
                p[2]=(short)f2bf(bv[j].z); p[3]=(short)f2bf(bv[j].w);
                *(short4v*)((char*)Bs + wX[j]) = p;
            }
        }
    }

    // epilogue: C/D layout col = l&15, row = (l>>4)*4 + reg
    const int rbase = (l >> 4)*4, cl = l & 15;
    #pragma unroll
    for (int h = 0; h < 2; ++h)
        #pragma unroll
        for (int i = 0; i < 4; ++i)
            #pragma unroll
            for (int j = 0; j < 4; ++j) {
                int m = h*256 + wr*64 + i*16 + rbase;
                int n = n0 + wc*64 + j*16 + cl;
                float* p = part + ((size_t)z*MPAD + m)*NPAD + n;
                #pragma unroll
                for (int r = 0; r < 4; ++r) p[(size_t)r*NPAD] = acc[h][i][j][r];
            }
}

// ---------------------------------------------------------------------------
// build_spat: spat[b][fr][c] = history (fr<30) | sum of KSPLIT partials
// ---------------------------------------------------------------------------
__global__ __launch_bounds__(256) void build_spat(
    const float* __restrict__ hist, const float* __restrict__ part,
    float* __restrict__ spat)
{
    int idx = blockIdx.x*256 + threadIdx.x;
    if (idx >= BB*NFRM*CC) return;
    int c   = idx % CC;
    int rem = idx / CC;
    int fr  = rem % NFRM;
    int b   = rem / NFRM;
    float v;
    if (fr < NHIST) {
        v = hist[(b*NHIST + fr)*CC + c];
    } else {
        int m = b*NJIT + (fr - NHIST);
        v = 0.f;
        #pragma unroll
        for (int kp = 0; kp < KSPLIT; ++kp)
            v += part[((size_t)kp*MPAD + m)*NPAD + c];
    }
    spat[idx] = v;
}

// ---------------------------------------------------------------------------
// conv_loss: per (b,c) gather+upsample -> depthwise conv (chunked-8 rolling
// window, all-static register indexing) -> loss partial. One wave per block.
// ---------------------------------------------------------------------------
__global__ __launch_bounds__(64) void conv_loss(
    const float* __restrict__ spat, const int* __restrict__ sel,
    const float* __restrict__ wts,  const float* __restrict__ tc,
    const float* __restrict__ fb,   const float* __restrict__ spk,
    const float* __restrict__ tmask, float* __restrict__ lpart)
{
    __shared__ float tcs[256];
    __shared__ float ups[864];   // index t + (t>>3): conflict-free sliding window

    const int lane = threadIdx.x;
    const int c = blockIdx.x;
    const int b = blockIdx.y;

    for (int k = lane; k < 256; k += 64)
        tcs[k] = (k < KK) ? tc[c*KK + k] : 0.f;

    const float* spb = spat + (size_t)b*NFRM*CC + c;
    for (int tt = lane; tt < 768; tt += 64) {
        float v = 0.f;
        if (tt < NBINS) {
            int base = (b*NBINS + tt)*2;
            int s0 = sel[base], s1 = sel[base+1];
            float w0 = wts[base], w1 = wts[base+1];
            v = w0 * spb[s0*CC] + w1 * spb[s1*CC];
        }
        ups[tt + (tt >> 3)] = v;
    }
    __syncthreads();

    const int t0 = lane * 8;
    float u[16];
    #pragma unroll
    for (int j = 0; j < 16; ++j) { int q = t0 + j; u[j] = ups[q + (q >> 3)]; }

    float acc[8] = {};
    #pragma unroll 4
    for (int kc = 0; kc < 248; kc += 8) {
        #pragma unroll
        for (int kk = 0; kk < 8; ++kk) {
            float w2 = tcs[kc + kk];
            #pragma unroll
            for (int j = 0; j < 8; ++j) acc[j] += w2 * u[kk + j];
        }
        #pragma unroll
        for (int j = 0; j < 8; ++j) u[j] = u[j + 8];
        #pragma unroll
        for (int j = 0; j < 8; ++j) {
            int q = t0 + kc + 16 + j;
            u[j + 8] = ups[q + (q >> 3)];
        }
    }
    #pragma unroll
    for (int kk = 0; kk < 8; ++kk) {
        float w2 = tcs[248 + kk];
        #pragma unroll
        for (int j = 0; j < 8; ++j) acc[j] += w2 * u[kk + j];
    }

    const size_t bc = (size_t)b*CC + c;
    const float* fbp = fb  + bc*(TOUT+1);
    const float* sp  = spk + bc*NBINS + KK;
    const float* tm  = tmask + (size_t)b*TOUT;
    float lsum = 0.f;
    #pragma unroll
    for (int j = 0; j < 8; ++j) {
        int tt = t0 + j;
        if (tt < TOUT) {
            float g  = acc[j] + fbp[tt];
            float sv = sp[tt];
            lsum += (__expf(g) - sv*g) * tm[tt];
        }
    }
    #pragma unroll
    for (int off = 32; off > 0; off >>= 1)
        lsum += __shfl_down(lsum, off);
    if (lane == 0) lpart[bc] = lsum * MAGIC;
}

__global__ __launch_bounds__(256) void reduce_out(
    const float* __restrict__ lpart, float* __restrict__ out)
{
    __shared__ float red[256];
    int b = blockIdx.x, t = threadIdx.x;
    float s = 0.f;
    for (int i = t; i < CC; i += 256) s += lpart[(size_t)b*CC + i];
    red[t] = s; __syncthreads();
    for (int o = 128; o > 0; o >>= 1) {
        if (t < o) red[t] += red[t+o];
        __syncthreads();
    }
    if (t == 0) out[b] = red[0];
}

extern "C" void kernel_launch(void* const* d_in, const int* in_sizes, int n_in,
                              void* d_out, int out_size, void* d_ws, size_t ws_size,
                              hipStream_t stream) {
    const float* image = (const float*)d_in[0];
    const float* spk   = (const float*)d_in[1];
    const int*   eye   = (const int*)d_in[2];
    const float* tmask = (const float*)d_in[3];
    const int*   sel   = (const int*)d_in[4];
    const float* wts   = (const float*)d_in[5];
    const float* filt  = (const float*)d_in[6];
    const float* tc    = (const float*)d_in[7];
    const float* fb    = (const float*)d_in[8];
    const float* hist  = (const float*)d_in[9];
    float* out = (float*)d_out;

    unsigned short* Ap = (unsigned short*)d_ws;                 // 512*40960 bf16
    float* part  = (float*)(Ap + (size_t)MPAD*PP);              // 40*512*768 f32
    float* spat  = part + (size_t)KSPLIT*MPAD*NPAD;             // 8*90*700 f32
    float* lpart = spat + (size_t)BB*NFRM*CC;                   // 8*700 f32

    pack_a   <<<dim3(32, 20), 256, 0, stream>>>(image, eye, Ap);
    gemm_bf  <<<dim3(240), 512, 0, stream>>>(Ap, filt, part);
    build_spat<<<dim3((BB*NFRM*CC + 255)/256), 256, 0, stream>>>(hist, part, spat);
    conv_loss<<<dim3(CC, BB), 64, 0, stream>>>(spat, sel, wts, tc, fb, spk, tmask, lpart);
    reduce_out<<<dim3(BB), 256, 0, stream>>>(lpart, out);
}